// Round 9
// baseline (437.660 us; speedup 1.0000x reference)
//
#include <hip/hip_runtime.h>
#include <hip/hip_fp16.h>

#define T_DIM 2048
#define D_DIM 256
#define K_CODES 512
#define N_ROWS 131072
#define Q_ELEMS 33554432
#define FMARGIN 2.0e-4f

typedef __attribute__((ext_vector_type(8))) _Float16 f16x8;
typedef __attribute__((ext_vector_type(4))) _Float16 f16x4;
typedef __attribute__((ext_vector_type(4))) float f32x4;

// ws layout (bytes):
// [0, 2048)            norms (512 f32, numpy-pairwise-exact)
// [2048, 18432)        bsums (2048 f64, main partials)
// [20480, 36864)       bitmap (4096 u32; bit = row needs FULL exact rescan, rare)
// [36864, 299008)      e16: f16(512*e) [512][256]
// [299008, 303104)     bsums2 (512 f64, xpose sum(x^2) partials)
// [303104, 67412 KB)   x16: f16(x) [131072][256] row-major (64 MB)  -- MODE 2 only

__device__ __forceinline__ float comb8(const float* r) {
  return ((r[0] + r[1]) + (r[2] + r[3])) + ((r[4] + r[5]) + (r[6] + r[7]));
}

// top-3 merge: (m,id,m2,id2,m3) <- merge with (om,oi,om2,oi2,om3); ties -> lower id
__device__ __forceinline__ void merge3(float& m, int& id, float& m2, int& id2, float& m3,
                                       float om, int oi, float om2, int oi2, float om3) {
  if (om < m || (om == m && oi < id)) {
    float tm = m; int ti = id; float tm2 = m2;
    m = om; id = oi;
    if (om2 < tm || (om2 == tm && oi2 < ti)) { m2 = om2; id2 = oi2; m3 = fminf(tm, om3); }
    else { m2 = tm; id2 = ti; m3 = fminf(tm2, om2); }
  } else {
    if (om < m2 || (om == m2 && oi < id2)) { float tm2 = m2; m2 = om; id2 = oi; m3 = fminf(tm2, om2); }
    else { m3 = fminf(m3, om); }
  }
}

__global__ __launch_bounds__(256) void vq_prep(const float* __restrict__ e,
                                               float* __restrict__ norms,
                                               unsigned short* __restrict__ e16,
                                               unsigned* __restrict__ bitmap,
                                               double* __restrict__ bsums2,
                                               int use_ws) {
  __shared__ float srow[D_DIM];
  int k = blockIdx.x, t = threadIdx.x;
  float v = e[k * D_DIM + t];
  srow[t] = v;
  if (use_ws) e16[k * D_DIM + t] = __half_as_ushort(__float2half(512.0f * v));
  if (t < 8) bitmap[k * 8 + t] = 0u;
  if (t == 8) bsums2[k] = 0.0;   // k < 512 == bsums2 extent
  __syncthreads();
  if (t == 0) {
    float res[2];
    #pragma unroll
    for (int h = 0; h < 2; ++h) {
      float r[8];
      #pragma unroll
      for (int j = 0; j < 8; ++j) { float a = srow[h * 128 + j]; r[j] = __fmul_rn(a, a); }
      for (int i = 8; i < 128; i += 8)
        #pragma unroll
        for (int j = 0; j < 8; ++j) { float a = srow[h * 128 + i + j]; r[j] = __fadd_rn(r[j], __fmul_rn(a, a)); }
      res[h] = comb8(r);
    }
    norms[k] = __fadd_rn(res[0], res[1]);
  }
}

// Streaming transpose: x [B,D,T] fp32 -> x16 [N][256] f16 (row-major), plus sum(x^2).
// Reads 1KB-sequential per d-row (256t x 256d tile), writes fully contiguous 128KB spans.
__global__ __launch_bounds__(512, 1) void vq_xpose(const float* __restrict__ x,
                                                   unsigned short* __restrict__ x16,
                                                   double* __restrict__ bsums2) {
  __shared__ unsigned short tl[256 * 264];   // [t][d], pitch 264 f16
  __shared__ double dred[8];
  const int tx = threadIdx.x;
  const int blk = blockIdx.x;                // 512 = 64 b x 8 tc
  const int b = blk >> 3, t0 = (blk & 7) * 256;
  const int w = tx >> 6, lane = tx & 63;
  const int lt = lane & 15, ld = lane >> 4;

  float xsq = 0.f;
  #pragma unroll
  for (int dbi = 0; dbi < 2; ++dbi) {
    const int dbase = w * 32 + dbi * 16;
    #pragma unroll
    for (int tp = 0; tp < 4; ++tp) {
      float4 v[4];
      #pragma unroll
      for (int rd = 0; rd < 4; ++rd) {
        int d = dbase + ld * 4 + rd;
        v[rd] = *(const float4*)(x + ((size_t)(b * 256 + d)) * 2048 + t0 + tp * 64 + lt * 4);
      }
      #pragma unroll
      for (int rd = 0; rd < 4; ++rd) {
        xsq = fmaf(v[rd].x, v[rd].x, xsq); xsq = fmaf(v[rd].y, v[rd].y, xsq);
        xsq = fmaf(v[rd].z, v[rd].z, xsq); xsq = fmaf(v[rd].w, v[rd].w, xsq);
      }
      #pragma unroll
      for (int j = 0; j < 4; ++j) {       // 4x4 in-register micro-transpose
        f16x4 pk;
        pk[0] = (_Float16)(((const float*)&v[0])[j]);
        pk[1] = (_Float16)(((const float*)&v[1])[j]);
        pk[2] = (_Float16)(((const float*)&v[2])[j]);
        pk[3] = (_Float16)(((const float*)&v[3])[j]);
        int tloc = tp * 64 + lt * 4 + j;
        *(f16x4*)&tl[tloc * 264 + dbase + ld * 4] = pk;
      }
    }
  }
  __syncthreads();
  const size_t dstb = ((size_t)(b * 2048 + t0)) * 256;
  #pragma unroll 4
  for (int i = 0; i < 32; ++i) {
    int r = w * 32 + i;
    f16x4 pk = *(const f16x4*)&tl[r * 264 + lane * 4];
    *(f16x4*)(x16 + dstb + (size_t)r * 256 + lane * 4) = pk;
  }
  double dv = (double)xsq;
  #pragma unroll
  for (int o = 32; o > 0; o >>= 1) dv += __shfl_down(dv, o, 64);
  if (lane == 0) dred[w] = dv;
  __syncthreads();
  if (tx == 0) {
    double s = 0.0;
    #pragma unroll
    for (int i = 0; i < 8; ++i) s += dred[i];
    bsums2[blk] = s;
  }
}

// MODE 2: A-frags direct from x16 (registers, no x-LDS); 1: round-8 staging + e16;
// 0: staging + inline e conversion. NOTE launch_bounds 2nd arg acts as a CUDA-style
// VGPR cap (65536/threads/arg) -- (256,1) leaves 256 available (round-7 lesson).
template <int MODE>
__global__ __launch_bounds__(256, 1) void vq_main(
    const float* __restrict__ x, const float* __restrict__ e,
    const float* __restrict__ norms, const unsigned short* __restrict__ e16,
    const unsigned short* __restrict__ x16,
    float* __restrict__ out_q, float* __restrict__ out_idx,
    double* __restrict__ bsums, unsigned* __restrict__ bitmap) {
  __shared__ unsigned short xlds[(MODE == 2) ? 16 : 64 * 256];
  __shared__ float nlds[K_CODES];
  __shared__ float wredm[2][64], wredm2[2][64], wredm3[2][64];
  __shared__ int   wredi[2][64], wredi2[2][64];
  __shared__ float rmin[64];
  __shared__ int   widx[64];
  __shared__ float xrow[256];
  __shared__ float xr16[16];
  __shared__ double dred[4];

  const int tx = threadIdx.x;
  const int blk = blockIdx.x;                 // 2048
  const int b = blk >> 5, t0 = (blk & 31) * 64;
  const int lane = tx & 63, w = tx >> 6;
  const int wm = w & 1, wn = w >> 1;          // rows wm*32..+32, code-half wn
  const int c = lane & 15, g = lane >> 4;

  nlds[tx] = norms[tx];
  nlds[tx + 256] = norms[tx + 256];

  float xsum = 0.f;
  f16x8 af2[2][8];
  if (MODE == 2) {
    // A-frags straight from x16 rows (block-contiguous 32KB span)
    const unsigned short* xr0 = x16 + ((size_t)(blk * 64 + wm * 32 + c)) * 256;
    #pragma unroll
    for (int mi = 0; mi < 2; ++mi)
      #pragma unroll
      for (int ch = 0; ch < 8; ++ch)
        af2[mi][ch] = *(const f16x8*)(xr0 + mi * 16 * 256 + ch * 32 + g * 8);
    __syncthreads();  // nlds visibility
  } else {
    // round-8 staging: fp32 -> f16 swizzled LDS (paired-d b32 writes)
    const int f4 = tx >> 4, dd = tx & 15;
    const float* xb = x + (size_t)b * (D_DIM * T_DIM) + t0 + f4 * 4;
    unsigned* xl32 = (unsigned*)xlds;
    #pragma unroll
    for (int p = 0; p < 8; ++p) {
      int d0 = p * 32 + dd * 2;
      float4 va = *(const float4*)(xb + (size_t)d0 * T_DIM);
      float4 vb = *(const float4*)(xb + (size_t)(d0 + 1) * T_DIM);
      int chunk = d0 >> 3;
      float aa[4] = {va.x, va.y, va.z, va.w};
      float bbv[4] = {vb.x, vb.y, vb.z, vb.w};
      #pragma unroll
      for (int j = 0; j < 4; ++j) {
        int row = f4 * 4 + j;
        int slot = (chunk & 24) | ((chunk ^ row) & 7);
        unsigned u = (unsigned)__half_as_ushort(__float2half(aa[j])) |
                     ((unsigned)__half_as_ushort(__float2half(bbv[j])) << 16);
        xl32[row * 128 + slot * 4 + ((d0 & 7) >> 1)] = u;
        xsum = fmaf(aa[j], aa[j], xsum);
        xsum = fmaf(bbv[j], bbv[j], xsum);
      }
    }
    __syncthreads();
  }

  // ---- per-slot running top-3; slot si = mi*4+q -> row wm*32+mi*16+g*4+q
  float m[8], m2[8], m3[8];
  int id[8], id2[8];
  #pragma unroll
  for (int si = 0; si < 8; ++si) { m[si] = 3.4e38f; m2[si] = 3.4e38f; m3[si] = 3.4e38f; id[si] = 0; id2[si] = 0; }

  for (int cq = 0; cq < 8; ++cq) {            // 64 codes per cq
    const int cb = cq * 64 + wn * 32;
    f32x4 acc[2][2];
    #pragma unroll
    for (int mi = 0; mi < 2; ++mi) { acc[mi][0] = (f32x4){0,0,0,0}; acc[mi][1] = (f32x4){0,0,0,0}; }

    #pragma unroll
    for (int ch = 0; ch < 8; ++ch) {
      f16x8 bf[2];
      if (MODE >= 1) {
        bf[0] = *(const f16x8*)(e16 + (size_t)(cb + c) * D_DIM + ch * 32 + g * 8);
        bf[1] = *(const f16x8*)(e16 + (size_t)(cb + 16 + c) * D_DIM + ch * 32 + g * 8);
      } else {
        #pragma unroll
        for (int nj = 0; nj < 2; ++nj) {
          const float* ep = e + (size_t)(cb + nj * 16 + c) * D_DIM + ch * 32 + g * 8;
          float4 u0 = *(const float4*)ep;
          float4 u1 = *(const float4*)(ep + 4);
          f16x8 r;
          r[0] = (_Float16)(512.f * u0.x); r[1] = (_Float16)(512.f * u0.y);
          r[2] = (_Float16)(512.f * u0.z); r[3] = (_Float16)(512.f * u0.w);
          r[4] = (_Float16)(512.f * u1.x); r[5] = (_Float16)(512.f * u1.y);
          r[6] = (_Float16)(512.f * u1.z); r[7] = (_Float16)(512.f * u1.w);
          bf[nj] = r;
        }
      }
      #pragma unroll
      for (int mi = 0; mi < 2; ++mi) {
        f16x8 af;
        if (MODE == 2) {
          af = af2[mi][ch];
        } else {
          int row = wm * 32 + mi * 16 + c;
          int chunk = ch * 4 + g;
          int slot = (chunk & 24) | ((chunk ^ row) & 7);
          af = *(const f16x8*)&xlds[row * 256 + slot * 8];
        }
        acc[mi][0] = __builtin_amdgcn_mfma_f32_16x16x32_f16(af, bf[0], acc[mi][0], 0, 0, 0);
        acc[mi][1] = __builtin_amdgcn_mfma_f32_16x16x32_f16(af, bf[1], acc[mi][1], 0, 0, 0);
      }
    }
    // fold (codes ascending: nj 0 then 1); sv = nrm - 2*(dot/512)
    #pragma unroll
    for (int nj = 0; nj < 2; ++nj) {
      float nrm = nlds[cb + nj * 16 + c];
      int code = cb + nj * 16 + c;
      #pragma unroll
      for (int mi = 0; mi < 2; ++mi)
        #pragma unroll
        for (int q = 0; q < 4; ++q) {
          int si = mi * 4 + q;
          float sv = fmaf(-0.00390625f, acc[mi][nj][q], nrm);
          if (sv < m[si])       { m3[si] = m2[si]; m2[si] = m[si]; id2[si] = id[si]; m[si] = sv; id[si] = code; }
          else if (sv < m2[si]) { m3[si] = m2[si]; m2[si] = sv; id2[si] = code; }
          else if (sv < m3[si]) { m3[si] = sv; }
        }
    }
  }

  // ---- cross-lane (16 codes over c) top-3 butterfly
  #pragma unroll
  for (int si = 0; si < 8; ++si) {
    float M = m[si], M2 = m2[si], M3 = m3[si];
    int I = id[si], I2 = id2[si];
    #pragma unroll
    for (int off = 1; off < 16; off <<= 1) {
      float om = __shfl_xor(M, off, 64), om2 = __shfl_xor(M2, off, 64), om3 = __shfl_xor(M3, off, 64);
      int oi = __shfl_xor(I, off, 64), oi2 = __shfl_xor(I2, off, 64);
      merge3(M, I, M2, I2, M3, om, oi, om2, oi2, om3);
    }
    if (c == 0) {
      int row = wm * 32 + (si >> 2) * 16 + g * 4 + (si & 3);
      wredm[wn][row] = M; wredm2[wn][row] = M2; wredm3[wn][row] = M3;
      wredi[wn][row] = I; wredi2[wn][row] = I2;
    }
  }
  __syncthreads();

  // ---- wave 0: merge code-halves, flag, inline exact pair-resolution
  if (tx < 64) {
    float M = wredm[0][tx], M2 = wredm2[0][tx], M3 = wredm3[0][tx];
    int I = wredi[0][tx], I2 = wredi2[0][tx];
    merge3(M, I, M2, I2, M3, wredm[1][tx], wredi[1][tx], wredm2[1][tx], wredi2[1][tx], wredm3[1][tx]);
    rmin[tx] = M;
    widx[tx] = I;
    bool rescan = (M3 - M <= FMARGIN);
    bool pairf  = (M2 - M <= FMARGIN) && !rescan;
    unsigned long long bm3 = __ballot(rescan);
    if (lane == 0) {
      bitmap[blk * 2] = (unsigned)bm3;
      bitmap[blk * 2 + 1] = (unsigned)(bm3 >> 32);
    }
    unsigned long long bm = __ballot(pairf);
    while (bm) {
      int row = __ffsll(bm) - 1; bm &= bm - 1;
      int k1 = __shfl(I, row), k2 = __shfl(I2, row);
      int ka = min(k1, k2), kb = max(k1, k2);
      int trow = t0 + row;
      #pragma unroll
      for (int j = 0; j < 4; ++j)
        xrow[lane + 64 * j] = x[((size_t)(b * 256 + lane + 64 * j)) * 2048 + trow];
      asm volatile("s_waitcnt vmcnt(0) lgkmcnt(0)" ::: "memory");
      if (lane < 16) {  // exact numpy-pairwise ||x||^2: 16 chains
        int h = lane >> 3, jj = lane & 7;
        float a0 = xrow[h * 128 + jj];
        float r = __fmul_rn(a0, a0);
        for (int i = 1; i < 16; ++i) {
          float a = xrow[h * 128 + i * 8 + jj];
          r = __fadd_rn(r, __fmul_rn(a, a));
        }
        xr16[lane] = r;
      }
      asm volatile("s_waitcnt lgkmcnt(0)" ::: "memory");
      float sv = 0.f;
      if (lane < 2) {
        int k = lane ? kb : ka;
        float a = 0.f;
        const float* ep = e + (size_t)k * D_DIM;
        #pragma unroll 4
        for (int d = 0; d < 256; ++d) a = __fmaf_rn(xrow[d], ep[d], a);
        float xx = __fadd_rn(comb8(&xr16[0]), comb8(&xr16[8]));
        float t1 = __fadd_rn(xx, nlds[k]);
        sv = t1 - 2.0f * a;
      }
      float s0 = __shfl(sv, 0), s1 = __shfl(sv, 1);
      if (lane == 0) widx[row] = (s1 < s0) ? kb : ka;
    }
  }
  __syncthreads();

  // ---- writes: idx + fused q-gather (final widx)
  if (tx < 64) out_idx[(size_t)blk * 64 + tx] = (float)widx[tx];
  #pragma unroll 4
  for (int i = 0; i < 16; ++i) {
    int row = w * 16 + i;
    int k = widx[row];
    float4 ev = *(const float4*)(e + (size_t)k * D_DIM + lane * 4);
    *(float4*)(out_q + ((size_t)blk * 64 + row) * D_DIM + lane * 4) = ev;
  }

  // ---- loss partial: sum(row min scores) (+ sum(x^2) when staged here)
  double dv = (double)xsum + ((tx < 64) ? (double)rmin[tx] : 0.0);
  #pragma unroll
  for (int o = 32; o > 0; o >>= 1) dv += __shfl_down(dv, o, 64);
  if (lane == 0) dred[w] = dv;
  __syncthreads();
  if (tx == 0) bsums[blk] = (dred[0] + dred[1]) + (dred[2] + dred[3]);
}

// Full exact rescan (wave-per-row, lane-parallel codes) for rare >=3-way rows.
__global__ __launch_bounds__(64) void vq_fixup(
    const float* __restrict__ x, const float* __restrict__ e,
    const float* __restrict__ norms, const unsigned* __restrict__ bitmap,
    float* __restrict__ out_q, float* __restrict__ out_idx) {
  __shared__ float xrow[256];
  __shared__ float xr16[16];
  const int blk = blockIdx.x, lane = threadIdx.x;
  unsigned long long bm = (unsigned long long)bitmap[blk * 2] |
                          ((unsigned long long)bitmap[blk * 2 + 1] << 32);
  if (!bm) return;
  const int b = blk >> 5, t0 = (blk & 31) * 64;
  while (bm) {
    int row = __ffsll(bm) - 1; bm &= bm - 1;
    int trow = t0 + row;
    #pragma unroll
    for (int j = 0; j < 4; ++j)
      xrow[lane + 64 * j] = x[((size_t)(b * 256 + lane + 64 * j)) * 2048 + trow];
    asm volatile("s_waitcnt vmcnt(0) lgkmcnt(0)" ::: "memory");
    if (lane < 16) {
      int h = lane >> 3, jj = lane & 7;
      float a0 = xrow[h * 128 + jj];
      float r = __fmul_rn(a0, a0);
      for (int i = 1; i < 16; ++i) {
        float a = xrow[h * 128 + i * 8 + jj];
        r = __fadd_rn(r, __fmul_rn(a, a));
      }
      xr16[lane] = r;
    }
    asm volatile("s_waitcnt lgkmcnt(0)" ::: "memory");
    float xx = __fadd_rn(comb8(&xr16[0]), comb8(&xr16[8]));
    float am[8];
    #pragma unroll
    for (int cc = 0; cc < 8; ++cc) am[cc] = 0.f;
    const float* eb = e + (size_t)(lane * 8) * D_DIM;
    for (int d4 = 0; d4 < 64; ++d4) {
      float4 xv = *(const float4*)&xrow[d4 * 4];
      #pragma unroll
      for (int cc = 0; cc < 8; ++cc) {
        float4 ev = *(const float4*)(eb + (size_t)cc * D_DIM + d4 * 4);
        am[cc] = __fmaf_rn(xv.x, ev.x, am[cc]);
        am[cc] = __fmaf_rn(xv.y, ev.y, am[cc]);
        am[cc] = __fmaf_rn(xv.z, ev.z, am[cc]);
        am[cc] = __fmaf_rn(xv.w, ev.w, am[cc]);
      }
    }
    float lm = 3.4e38f; int lk = 0;
    #pragma unroll
    for (int cc = 0; cc < 8; ++cc) {
      int k = lane * 8 + cc;
      float t1 = __fadd_rn(xx, norms[k]);
      float sv = t1 - 2.0f * am[cc];
      if (sv < lm) { lm = sv; lk = k; }
    }
    #pragma unroll
    for (int off = 1; off < 64; off <<= 1) {
      float om = __shfl_xor(lm, off, 64);
      int oi = __shfl_xor(lk, off, 64);
      if (om < lm || (om == lm && oi < lk)) { lm = om; lk = oi; }
    }
    if (lane == 0) out_idx[(size_t)blk * 64 + row] = (float)lk;
    int wk = __shfl(lk, 0);
    float4 ev = *(const float4*)(e + (size_t)wk * D_DIM + lane * 4);
    *(float4*)(out_q + ((size_t)blk * 64 + row) * D_DIM + lane * 4) = ev;
  }
}

__global__ __launch_bounds__(256) void vq_final(const double* __restrict__ bs,
                                                const double* __restrict__ bs2,
                                                float* __restrict__ out_loss) {
  __shared__ double sred[4];
  int t = threadIdx.x;
  double s = 0.0;
  for (int i = t; i < 2048; i += 256) s += bs[i];
  for (int i = t; i < 512; i += 256) s += bs2[i];
  #pragma unroll
  for (int o = 32; o > 0; o >>= 1) s += __shfl_down(s, o, 64);
  if ((t & 63) == 0) sred[t >> 6] = s;
  __syncthreads();
  if (t == 0)
    out_loss[0] = (float)(0.25 * (((sred[0] + sred[1]) + (sred[2] + sred[3])) / (double)Q_ELEMS));
}

extern "C" void kernel_launch(void* const* d_in, const int* in_sizes, int n_in,
                              void* d_out, int out_size, void* d_ws, size_t ws_size,
                              hipStream_t stream) {
  const float* x = (const float*)d_in[0];
  const float* e = (const float*)d_in[1];
  float* out = (float*)d_out;
  float* out_q = out;
  float* out_loss = out + Q_ELEMS;
  float* out_idx = out + Q_ELEMS + 1;

  char* ws = (char*)d_ws;
  float* norms = (float*)ws;
  double* bsums = (double*)(ws + 2048);
  unsigned* bitmap = (unsigned*)(ws + 20480);
  unsigned short* e16 = (unsigned short*)(ws + 36864);
  double* bsums2 = (double*)(ws + 299008);
  unsigned short* x16 = (unsigned short*)(ws + 303104);

  int mode = (ws_size >= 67411968ull) ? 2 : ((ws_size >= 299008) ? 1 : 0);

  vq_prep<<<K_CODES, 256, 0, stream>>>(e, norms, e16, bitmap, bsums2, mode >= 1);
  if (mode == 2) {
    vq_xpose<<<512, 512, 0, stream>>>(x, x16, bsums2);
    vq_main<2><<<N_ROWS / 64, 256, 0, stream>>>(x, e, norms, e16, x16, out_q, out_idx, bsums, bitmap);
  } else if (mode == 1) {
    vq_main<1><<<N_ROWS / 64, 256, 0, stream>>>(x, e, norms, e16, x16, out_q, out_idx, bsums, bitmap);
  } else {
    vq_main<0><<<N_ROWS / 64, 256, 0, stream>>>(x, e, norms, e16, x16, out_q, out_idx, bsums, bitmap);
  }
  vq_fixup<<<N_ROWS / 64, 64, 0, stream>>>(x, e, norms, bitmap, out_q, out_idx);
  vq_final<<<1, 256, 0, stream>>>(bsums, bsums2, out_loss);
}

// Round 10
// 421.188 us; speedup vs baseline: 1.0391x; 1.0391x over previous
//
#include <hip/hip_runtime.h>
#include <hip/hip_fp16.h>

#define T_DIM 2048
#define D_DIM 256
#define K_CODES 512
#define N_ROWS 131072
#define Q_ELEMS 33554432
#define FMARGIN 2.0e-4f

typedef __attribute__((ext_vector_type(8))) _Float16 f16x8;
typedef __attribute__((ext_vector_type(8))) short s16x8;
typedef __attribute__((ext_vector_type(4))) float f32x4;

// ws layout (bytes) -- total 67411968, == round-9 proven footprint:
// [0, 2048)        norms (512 f32, numpy-pairwise-exact)
// [2048, 18432)    bsums (2048 f64, main loss partials)
// [20480, 36864)   bitmap (4096 u32, flag bits; main writes every word)
// [36864, 40960)   bsums2 (512 f64, xpose sum(x^2) partials)
// [40960, 303104)  e16: f16(512*e), k-granule layout: u16 idx =
//                  (k>>5)*8192 + (d>>3)*256 + (k&31)*8 + (d&7)
// [303104, 67411968) x16: f16(x) rows, k-granule layout per 64-row span:
//                  u16 idx = (n>>6)*16384 + (d>>3)*512 + (n&63)*8 + (d&7)
// k2 for flagged rows lives in out_q[n] (scratch until vq_gather).

__device__ __forceinline__ float comb8(const float* r) {
  return ((r[0] + r[1]) + (r[2] + r[3])) + ((r[4] + r[5]) + (r[6] + r[7]));
}

__device__ __forceinline__ void merge3(float& m, int& id, float& m2, int& id2, float& m3,
                                       float om, int oi, float om2, int oi2, float om3) {
  if (om < m || (om == m && oi < id)) {
    float tm = m; int ti = id; float tm2 = m2;
    m = om; id = oi;
    if (om2 < tm || (om2 == tm && oi2 < ti)) { m2 = om2; id2 = oi2; m3 = fminf(tm, om3); }
    else { m2 = tm; id2 = ti; m3 = fminf(tm2, om2); }
  } else {
    if (om < m2 || (om == m2 && oi < id2)) { float tm2 = m2; m2 = om; id2 = oi; m3 = fminf(tm2, om2); }
    else { m3 = fminf(m3, om); }
  }
}

__device__ __forceinline__ void gl_lds16(const void* g, void* l) {
  __builtin_amdgcn_global_load_lds(
      (const __attribute__((address_space(1))) unsigned int*)g,
      (__attribute__((address_space(3))) unsigned int*)l, 16, 0, 0);
}

__global__ __launch_bounds__(256) void vq_prep(const float* __restrict__ e,
                                               float* __restrict__ norms,
                                               unsigned short* __restrict__ e16) {
  __shared__ float srow[D_DIM];
  int k = blockIdx.x, t = threadIdx.x;
  float v = e[k * D_DIM + t];
  srow[t] = v;
  e16[(k >> 5) * 8192 + (t >> 3) * 256 + (k & 31) * 8 + (t & 7)] =
      __half_as_ushort(__float2half(512.0f * v));
  __syncthreads();
  if (t == 0) {
    float res[2];
    #pragma unroll
    for (int h = 0; h < 2; ++h) {
      float r[8];
      #pragma unroll
      for (int j = 0; j < 8; ++j) { float a = srow[h * 128 + j]; r[j] = __fmul_rn(a, a); }
      for (int i = 8; i < 128; i += 8)
        #pragma unroll
        for (int j = 0; j < 8; ++j) { float a = srow[h * 128 + i + j]; r[j] = __fadd_rn(r[j], __fmul_rn(a, a)); }
      res[h] = comb8(r);
    }
    norms[k] = __fadd_rn(res[0], res[1]);
  }
}

// x [B,D,T] fp32 -> x16 f16 in k-granule layout; contiguous 1KB reads per wave-row,
// fully linear b128 LDS->global copy out; also sum(x^2).
__global__ __launch_bounds__(512, 1) void vq_xpose(const float* __restrict__ x,
                                                   unsigned short* __restrict__ x16,
                                                   double* __restrict__ bsums2) {
  __shared__ unsigned short tlu[32 * 2048];   // 128 KB: [kg 32][t 256][8 u16]
  __shared__ double dred[8];
  const int tx = threadIdx.x, blk = blockIdx.x;     // 512 = 64 b x 8 t-chunks
  const int b = blk >> 3, t0 = (blk & 7) * 256;
  const int w = tx >> 6, lane = tx & 63;

  float xsq = 0.f;
  #pragma unroll
  for (int g8 = 0; g8 < 4; ++g8) {
    unsigned short pk[4][8];
    #pragma unroll
    for (int dj = 0; dj < 8; ++dj) {
      int d = w * 32 + g8 * 8 + dj;
      float4 v = *(const float4*)(x + (size_t)(b * 256 + d) * 2048 + t0 + lane * 4);
      xsq = fmaf(v.x, v.x, xsq); xsq = fmaf(v.y, v.y, xsq);
      xsq = fmaf(v.z, v.z, xsq); xsq = fmaf(v.w, v.w, xsq);
      pk[0][dj] = __half_as_ushort(__float2half(v.x));
      pk[1][dj] = __half_as_ushort(__float2half(v.y));
      pk[2][dj] = __half_as_ushort(__float2half(v.z));
      pk[3][dj] = __half_as_ushort(__float2half(v.w));
    }
    int kg = w * 4 + g8;
    #pragma unroll
    for (int j = 0; j < 4; ++j)
      *(s16x8*)&tlu[kg * 2048 + (lane * 4 + j) * 8] = *(s16x8*)&pk[j][0];
  }
  __syncthreads();
  const size_t obase = (size_t)(b * 2048 + t0) * 256;   // u16 units
  #pragma unroll 4
  for (int i = 0; i < 16; ++i) {
    int q = tx + i * 512;
    s16x8 vv = *(const s16x8*)&tlu[((q >> 6) & 31) * 2048 + ((q >> 11) * 64 + (q & 63)) * 8];
    *(s16x8*)(x16 + obase + (size_t)q * 8) = vv;
  }
  double dv = (double)xsq;
  #pragma unroll
  for (int o = 32; o > 0; o >>= 1) dv += __shfl_down(dv, o, 64);
  if (lane == 0) dred[w] = dv;
  __syncthreads();
  if (tx == 0) {
    double s = 0.0;
    #pragma unroll
    for (int i = 0; i < 8; ++i) s += dred[i];
    bsums2[blk] = s;
  }
}

// Pure MFMA GEMM+argmin: A once + B dbuf via gl_lds, counted vmcnt, no global
// loads in the inner loop, no serial sections. Writes idx (approx), rmin-loss,
// bitmap + k2 (in out_q scratch). q written later by vq_gather.
__global__ __launch_bounds__(256, 1) void vq_main(
    const float* __restrict__ norms, const unsigned short* __restrict__ e16,
    const unsigned short* __restrict__ x16,
    float* __restrict__ out_qk2, float* __restrict__ out_idx,
    double* __restrict__ bsums, unsigned* __restrict__ bitmap) {
  __shared__ unsigned short Au[16384];        // 32 KB A tile (64 rows, k-granule)
  __shared__ unsigned short Bu[2][8192];      // 2 x 16 KB B chunks (32 codes)
  __shared__ float nlds[K_CODES];
  __shared__ float wredm[2][64], wredm2[2][64], wredm3[2][64];
  __shared__ int   wredi[2][64], wredi2[2][64];
  __shared__ double dred[4];

  const int tx = threadIdx.x, blk = blockIdx.x;   // 2048 blocks x 64 rows
  const int lane = tx & 63, w = tx >> 6;
  const int wm = w & 1, wn = w >> 1;              // rows wm*32..+32, code-half wn*16
  const int c = lane & 15, g = lane >> 4;

  nlds[tx] = norms[tx];
  nlds[tx + 256] = norms[tx + 256];

  // prologue: A (8 loads) + B0 (4) + B1 (4)
  #pragma unroll
  for (int i = 0; i < 8; ++i)
    gl_lds16(x16 + (size_t)blk * 16384 + i * 2048 + tx * 8, &Au[i * 2048 + w * 512]);
  #pragma unroll
  for (int i = 0; i < 4; ++i)
    gl_lds16(e16 + i * 2048 + tx * 8, &Bu[0][i * 2048 + w * 512]);
  #pragma unroll
  for (int i = 0; i < 4; ++i)
    gl_lds16(e16 + 8192 + i * 2048 + tx * 8, &Bu[1][i * 2048 + w * 512]);
  asm volatile("s_waitcnt vmcnt(4)" ::: "memory");   // A + B0 arrived
  __syncthreads();

  // hoist A fragments (16 ds_read_b128, conflict-free contiguous)
  f16x8 af2[2][8];
  #pragma unroll
  for (int mi = 0; mi < 2; ++mi)
    #pragma unroll
    for (int ch = 0; ch < 8; ++ch)
      af2[mi][ch] = *(const f16x8*)&Au[(ch * 4 + g) * 512 + (wm * 32 + mi * 16 + c) * 8];

  float m[8], m2[8], m3[8];
  int id[8], id2[8];
  #pragma unroll
  for (int si = 0; si < 8; ++si) { m[si] = 3.4e38f; m2[si] = 3.4e38f; m3[si] = 3.4e38f; id[si] = 0; id2[si] = 0; }

  for (int it = 0; it < 16; ++it) {               // 32 codes per chunk
    const unsigned short* bb = &Bu[it & 1][0];
    f32x4 acc[2];
    acc[0] = (f32x4){0.f, 0.f, 0.f, 0.f};
    acc[1] = (f32x4){0.f, 0.f, 0.f, 0.f};
    #pragma unroll
    for (int ch = 0; ch < 8; ++ch) {
      f16x8 bf = *(const f16x8*)&bb[(ch * 4 + g) * 256 + (wn * 16 + c) * 8];
      acc[0] = __builtin_amdgcn_mfma_f32_16x16x32_f16(af2[0][ch], bf, acc[0], 0, 0, 0);
      acc[1] = __builtin_amdgcn_mfma_f32_16x16x32_f16(af2[1][ch], bf, acc[1], 0, 0, 0);
    }
    // fold this code into running top-3 (codes ascending over it)
    int code = it * 32 + wn * 16 + c;
    float nrm = nlds[code];
    #pragma unroll
    for (int mi = 0; mi < 2; ++mi)
      #pragma unroll
      for (int q = 0; q < 4; ++q) {
        int si = mi * 4 + q;
        float sv = fmaf(-0.00390625f, acc[mi][q], nrm);   // nrm - 2*dot/512
        if (sv < m[si])       { m3[si] = m2[si]; m2[si] = m[si]; id2[si] = id[si]; m[si] = sv; id[si] = code; }
        else if (sv < m2[si]) { m3[si] = m2[si]; m2[si] = sv; id2[si] = code; }
        else if (sv < m3[si]) { m3[si] = sv; }
      }
    __syncthreads();                              // done reading Bu[it&1]
    if (it < 14) {
      #pragma unroll
      for (int i = 0; i < 4; ++i)
        gl_lds16(e16 + (size_t)(it + 2) * 8192 + i * 2048 + tx * 8,
                 &Bu[it & 1][i * 2048 + w * 512]);
      asm volatile("s_waitcnt vmcnt(4)" ::: "memory");   // B[it+1] arrived
      __syncthreads();
    } else if (it == 14) {
      asm volatile("s_waitcnt vmcnt(0)" ::: "memory");
      __syncthreads();
    }
  }

  // cross-lane (16 codes over c) top-3 butterfly
  #pragma unroll
  for (int si = 0; si < 8; ++si) {
    float M = m[si], M2 = m2[si], M3 = m3[si];
    int I = id[si], I2 = id2[si];
    #pragma unroll
    for (int off = 1; off < 16; off <<= 1) {
      float om = __shfl_xor(M, off, 64), om2 = __shfl_xor(M2, off, 64), om3 = __shfl_xor(M3, off, 64);
      int oi = __shfl_xor(I, off, 64), oi2 = __shfl_xor(I2, off, 64);
      merge3(M, I, M2, I2, M3, om, oi, om2, oi2, om3);
    }
    if (c == 0) {
      int row = wm * 32 + (si >> 2) * 16 + g * 4 + (si & 3);
      wredm[wn][row] = M; wredm2[wn][row] = M2; wredm3[wn][row] = M3;
      wredi[wn][row] = I; wredi2[wn][row] = I2;
    }
  }
  __syncthreads();

  float myrmin = 0.f;
  if (tx < 64) {
    float M = wredm[0][tx], M2 = wredm2[0][tx], M3 = wredm3[0][tx];
    int I = wredi[0][tx], I2 = wredi2[0][tx];
    merge3(M, I, M2, I2, M3, wredm[1][tx], wredi[1][tx], wredm2[1][tx], wredi2[1][tx], wredm3[1][tx]);
    myrmin = M;
    int n = blk * 64 + tx;
    out_idx[n] = (float)I;
    bool rescan = (M3 - M <= FMARGIN);
    bool pairf  = (M2 - M <= FMARGIN) && !rescan;
    if (pairf | rescan) out_qk2[n] = pairf ? (float)I2 : 2048.0f;
    unsigned long long bm = __ballot(pairf | rescan);
    if (lane == 0) {
      bitmap[blk * 2] = (unsigned)bm;
      bitmap[blk * 2 + 1] = (unsigned)(bm >> 32);
    }
  }
  double dv = (double)myrmin;
  #pragma unroll
  for (int o = 32; o > 0; o >>= 1) dv += __shfl_down(dv, o, 64);
  if (lane == 0) dred[w] = dv;
  __syncthreads();
  if (tx == 0) bsums[blk] = (dred[0] + dred[1]) + (dred[2] + dred[3]);
}

// Lane-parallel exact pair resolution: 32 rows x 2 candidates = 64 independent
// bit-exact fp32 chains (numpy-replica, identical ops to validated rounds 6-9).
__global__ __launch_bounds__(256) void vq_resolve(
    const float* __restrict__ x, const float* __restrict__ e,
    const float* __restrict__ norms, const unsigned* __restrict__ bitmap,
    const float* __restrict__ k2buf, float* __restrict__ out_idx) {
  __shared__ float xs[32][257];
  __shared__ int list[64];
  __shared__ int lcount;
  const int blk = blockIdx.x, tx = threadIdx.x;
  const int n0 = blk * 64;
  if (tx == 0) {
    int cnt = 0;
    for (int wi = 0; wi < 2; ++wi) {
      unsigned u = bitmap[blk * 2 + wi];
      while (u) {
        int bit = __ffs(u) - 1;
        int row = wi * 32 + bit;
        if (k2buf[n0 + row] < 1000.0f) list[cnt++] = row;   // pairs only
        u &= u - 1;
      }
    }
    lcount = cnt;
  }
  __syncthreads();
  const int nf = lcount;
  if (nf == 0) return;
  const int ri = tx >> 3, dl = tx & 7;

  for (int c0 = 0; c0 < nf; c0 += 32) {
    int R = min(32, nf - c0);
    if (ri < R) {
      int n = n0 + list[c0 + ri];
      int b2 = n >> 11, t2 = n & 2047;
      for (int j = 0; j < 32; ++j) {
        int d = dl * 32 + j;
        xs[ri][d] = x[((size_t)(b2 * 256 + d)) * 2048 + t2];
      }
    }
    __syncthreads();
    if (tx < 64) {
      int pi = tx >> 1, cand = tx & 1;
      float sv = 0.f;
      int ka = 0, kb = 0, n = 0;
      bool act = pi < R;
      if (act) {
        n = n0 + list[c0 + pi];
        int i1 = (int)out_idx[n], i2 = (int)k2buf[n];
        ka = min(i1, i2); kb = max(i1, i2);
        int k = cand ? kb : ka;
        // exact numpy-pairwise ||x||^2
        float res[2];
        #pragma unroll
        for (int h = 0; h < 2; ++h) {
          float r8[8];
          #pragma unroll
          for (int j = 0; j < 8; ++j) { float a = xs[pi][h * 128 + j]; r8[j] = __fmul_rn(a, a); }
          for (int i = 8; i < 128; i += 8)
            #pragma unroll
            for (int j = 0; j < 8; ++j) { float a = xs[pi][h * 128 + i + j]; r8[j] = __fadd_rn(r8[j], __fmul_rn(a, a)); }
          res[h] = comb8(r8);
        }
        float xx = __fadd_rn(res[0], res[1]);
        float a = 0.f;
        const float* ep = e + (size_t)k * D_DIM;
        #pragma unroll 4
        for (int d = 0; d < 256; ++d) a = __fmaf_rn(xs[pi][d], ep[d], a);
        float t1 = __fadd_rn(xx, norms[k]);
        sv = t1 - 2.0f * a;
      }
      float so = __shfl_xor(sv, 1, 64);
      if (act && cand == 0)
        out_idx[n] = (float)((so < sv) ? kb : ka);   // tie -> ka (lower)
    }
    __syncthreads();
  }
}

// Full exact rescan for rare >=3-way rows (k2 sentinel >= 1000). idx only.
__global__ __launch_bounds__(64) void vq_fixup(
    const float* __restrict__ x, const float* __restrict__ e,
    const float* __restrict__ norms, const unsigned* __restrict__ bitmap,
    const float* __restrict__ k2buf, float* __restrict__ out_idx) {
  __shared__ float xrow[256];
  __shared__ float xr16[16];
  const int blk = blockIdx.x, lane = threadIdx.x;
  unsigned long long bm = (unsigned long long)bitmap[blk * 2] |
                          ((unsigned long long)bitmap[blk * 2 + 1] << 32);
  if (!bm) return;
  const int b = blk >> 5, t0 = (blk & 31) * 64;
  while (bm) {
    int row = __ffsll(bm) - 1; bm &= bm - 1;
    if (k2buf[blk * 64 + row] < 1000.0f) continue;   // pair rows: resolve's job
    int trow = t0 + row;
    #pragma unroll
    for (int j = 0; j < 4; ++j)
      xrow[lane + 64 * j] = x[((size_t)(b * 256 + lane + 64 * j)) * 2048 + trow];
    asm volatile("s_waitcnt vmcnt(0) lgkmcnt(0)" ::: "memory");
    if (lane < 16) {
      int h = lane >> 3, jj = lane & 7;
      float a0 = xrow[h * 128 + jj];
      float r = __fmul_rn(a0, a0);
      for (int i = 1; i < 16; ++i) {
        float a = xrow[h * 128 + i * 8 + jj];
        r = __fadd_rn(r, __fmul_rn(a, a));
      }
      xr16[lane] = r;
    }
    asm volatile("s_waitcnt lgkmcnt(0)" ::: "memory");
    float xx = __fadd_rn(comb8(&xr16[0]), comb8(&xr16[8]));
    float am[8];
    #pragma unroll
    for (int cc = 0; cc < 8; ++cc) am[cc] = 0.f;
    const float* eb = e + (size_t)(lane * 8) * D_DIM;
    for (int d4 = 0; d4 < 64; ++d4) {
      float4 xv = *(const float4*)&xrow[d4 * 4];
      #pragma unroll
      for (int cc = 0; cc < 8; ++cc) {
        float4 ev = *(const float4*)(eb + (size_t)cc * D_DIM + d4 * 4);
        am[cc] = __fmaf_rn(xv.x, ev.x, am[cc]);
        am[cc] = __fmaf_rn(xv.y, ev.y, am[cc]);
        am[cc] = __fmaf_rn(xv.z, ev.z, am[cc]);
        am[cc] = __fmaf_rn(xv.w, ev.w, am[cc]);
      }
    }
    float lm = 3.4e38f; int lk = 0;
    #pragma unroll
    for (int cc = 0; cc < 8; ++cc) {
      int k = lane * 8 + cc;
      float t1 = __fadd_rn(xx, norms[k]);
      float sv = t1 - 2.0f * am[cc];
      if (sv < lm) { lm = sv; lk = k; }
    }
    #pragma unroll
    for (int off = 1; off < 64; off <<= 1) {
      float om = __shfl_xor(lm, off, 64);
      int oi = __shfl_xor(lk, off, 64);
      if (om < lm || (om == lm && oi < lk)) { lm = om; lk = oi; }
    }
    if (lane == 0) out_idx[(size_t)blk * 64 + row] = (float)lk;
  }
}

// Final gather: q[n][:] = e[idx[n]][:]  (flat-buffer identity of the
// view/permute quirk, validated round 2).
__global__ __launch_bounds__(256) void vq_gather(const float* __restrict__ e,
                                                 const float* __restrict__ idxf,
                                                 float* __restrict__ out_q) {
  int tid = blockIdx.x * 256 + threadIdx.x;
  #pragma unroll
  for (int p = 0; p < 4; ++p) {
    int g = tid + p * (8192 * 256);            // float4 index
    int n = g >> 6;
    int kk = (int)idxf[n];
    float4 ev = ((const float4*)e)[kk * 64 + (g & 63)];
    ((float4*)out_q)[g] = ev;
  }
}

__global__ __launch_bounds__(256) void vq_final(const double* __restrict__ bs,
                                                const double* __restrict__ bs2,
                                                float* __restrict__ out_loss) {
  __shared__ double sred[4];
  int t = threadIdx.x;
  double s = 0.0;
  for (int i = t; i < 2048; i += 256) s += bs[i];
  for (int i = t; i < 512; i += 256) s += bs2[i];
  #pragma unroll
  for (int o = 32; o > 0; o >>= 1) s += __shfl_down(s, o, 64);
  if ((t & 63) == 0) sred[t >> 6] = s;
  __syncthreads();
  if (t == 0)
    out_loss[0] = (float)(0.25 * (((sred[0] + sred[1]) + (sred[2] + sred[3])) / (double)Q_ELEMS));
}

extern "C" void kernel_launch(void* const* d_in, const int* in_sizes, int n_in,
                              void* d_out, int out_size, void* d_ws, size_t ws_size,
                              hipStream_t stream) {
  const float* x = (const float*)d_in[0];
  const float* e = (const float*)d_in[1];
  float* out = (float*)d_out;
  float* out_q = out;
  float* out_loss = out + Q_ELEMS;
  float* out_idx = out + Q_ELEMS + 1;

  char* ws = (char*)d_ws;
  float* norms = (float*)ws;
  double* bsums = (double*)(ws + 2048);
  unsigned* bitmap = (unsigned*)(ws + 20480);
  double* bsums2 = (double*)(ws + 36864);
  unsigned short* e16 = (unsigned short*)(ws + 40960);
  unsigned short* x16 = (unsigned short*)(ws + 303104);
  // ws_size >= 67411968 proven by round 9 (MODE 2 ran); layout fits exactly.

  vq_prep<<<K_CODES, 256, 0, stream>>>(e, norms, e16);
  vq_xpose<<<512, 512, 0, stream>>>(x, x16, bsums2);
  vq_main<<<N_ROWS / 64, 256, 0, stream>>>(norms, e16, x16, out_q, out_idx, bsums, bitmap);
  vq_resolve<<<N_ROWS / 64, 256, 0, stream>>>(x, e, norms, bitmap, out_q, out_idx);
  vq_fixup<<<N_ROWS / 64, 64, 0, stream>>>(x, e, norms, bitmap, out_q, out_idx);
  vq_gather<<<8192, 256, 0, stream>>>(e, out_idx, out_q);
  vq_final<<<1, 256, 0, stream>>>(bsums, bsums2, out_loss);
}